// Round 1
// baseline (9334.899 us; speedup 1.0000x reference)
//
#include <hip/hip_runtime.h>
#include <cstddef>
#include <cstdint>

// ---------------- T5-Base config (fixed) ----------------
constexpr int Bz  = 4;
constexpr int Sq  = 512;     // SE == SD == 512
constexpr int Dm  = 768;
constexpr int Hh  = 12;
constexpr int HDm = 64;
constexpr int Mf  = 3072;
constexpr int Ll  = 6;
constexpr int Vv  = 32128;
constexpr int NT  = Bz * Sq;          // 2048 token rows
constexpr int NBK = 32;               // num relpos buckets
constexpr int QKVLD = 3 * Dm;         // 2304: fused qkv row stride
#define NEG_INF_F (-1e10f)

typedef _Float16 f16;
typedef _Float16 half8 __attribute__((ext_vector_type(8)));
typedef float f32x4 __attribute__((ext_vector_type(4)));

// ---------------- relative-position bucket LUT ----------------
__global__ void build_lut_kernel(int* __restrict__ lut_enc, int* __restrict__ lut_dec) {
    int t = blockIdx.x * blockDim.x + threadIdx.x;
    if (t >= 1023) return;
    int delta = t - 511;          // j - i
    {   // encoder: bidirectional, 16 buckets after halving, max_exact 8
        int n = -delta;
        int ret = 0;
        if (n < 0) { ret = 16; n = -n; }
        int b;
        if (n < 8) b = ret + n;
        else {
            int v = 8 + (int)(logf((float)n / 8.0f) / logf(16.0f) * 8.0f);
            if (v > 15) v = 15;
            b = ret + v;
        }
        lut_enc[t] = b;
    }
    {   // decoder self: unidirectional, 32 buckets, max_exact 16
        int n = delta < 0 ? -delta : 0;
        int b;
        if (n < 16) b = n;
        else {
            b = 16 + (int)(logf((float)n / 16.0f) / logf(8.0f) * 16.0f);
            if (b > 31) b = 31;
        }
        lut_dec[t] = b;
    }
}

// ---------------- embedding gather ----------------
__global__ void embed_kernel(const float* __restrict__ emb, const int* __restrict__ tok,
                             float* __restrict__ out) {
    int r = blockIdx.x;
    int t = tok[r];
    const float* e = emb + (size_t)t * Dm;
    float* o = out + (size_t)r * Dm;
    for (int d = threadIdx.x; d < Dm; d += 256) o[d] = e[d];
}

// ---------------- RMS norm (row = 768) ----------------
__global__ __launch_bounds__(256) void rmsnorm_kernel(const float* __restrict__ in,
                                                      const float* __restrict__ scale,
                                                      float* __restrict__ out) {
    __shared__ float red[8];
    const float* row = in + (size_t)blockIdx.x * Dm;
    float* orow      = out + (size_t)blockIdx.x * Dm;
    int tid = threadIdx.x;
    float a = row[tid], b = row[tid + 256], c = row[tid + 512];
    float s = a * a + b * b + c * c;
    for (int o = 32; o; o >>= 1) s += __shfl_down(s, o, 64);
    int wid = tid >> 6, lane = tid & 63;
    if (lane == 0) red[wid] = s;
    __syncthreads();
    if (tid == 0) red[4] = red[0] + red[1] + red[2] + red[3];
    __syncthreads();
    float r = 1.0f / sqrtf(red[4] * (1.0f / (float)Dm) + 1e-6f);
    orow[tid]       = a * r * scale[tid];
    orow[tid + 256] = b * r * scale[tid + 256];
    orow[tid + 512] = c * r * scale[tid + 512];
}

// ---------------- weight pack: fp32 [K][N] -> fragment-linear fp16 tiles ----------
// tile = 32(K) x 128(N). within tile, slot s (0..511):
//   n = (s>>6)*16 + (s&15), kslot = (s>>4)&3, covers k = kslot*8 + j (j=0..7)
// byte offset of slot = s*16. tile (nt, kt) at ((nt*ktiles)+kt)*8192 bytes.
// grid: (ntiles_per_weight, ktiles, n_weights)
__global__ __launch_bounds__(256) void pack_kernel(const float* __restrict__ w0,
                                                   const float* __restrict__ w1,
                                                   const float* __restrict__ w2,
                                                   f16* __restrict__ out,
                                                   int Nw) {
    const float* w = (blockIdx.z == 0) ? w0 : (blockIdx.z == 1 ? w1 : w2);
    const int ktiles = gridDim.y;
    const int nt = blockIdx.z * gridDim.x + blockIdx.x;
    const int kt = blockIdx.y;
    f16* otile = out + ((size_t)nt * ktiles + kt) * 4096;
    const int n0 = blockIdx.x * 128, k0 = kt * 32;
    const int tid = threadIdx.x;
#pragma unroll
    for (int p = 0; p < 2; ++p) {
        int s  = tid + p * 256;
        int nn = ((s >> 6) << 4) + (s & 15);
        int kk = ((s >> 4) & 3) << 3;
        const float* src = w + (size_t)(k0 + kk) * Nw + n0 + nn;
        half8 h;
#pragma unroll
        for (int j = 0; j < 8; ++j) h[j] = (f16)src[(size_t)j * Nw];
        *(half8*)((char*)otile + s * 16) = h;
    }
}

// ---------------- MFMA fp16 GEMM: C = A[MxK](fp32) @ Bp(packed fp16) ------------
// 128x128 tile, BK=32, 4 waves (2x2), each wave 64x64 = 4x4 frags of 16x16x32.
// A is converted fp32->fp16 during staging; LDS is fragment-linear (conflict-free).
__device__ inline half8 cvt8(float4 a, float4 b) {
    half8 h;
    h[0] = (f16)a.x; h[1] = (f16)a.y; h[2] = (f16)a.z; h[3] = (f16)a.w;
    h[4] = (f16)b.x; h[5] = (f16)b.y; h[6] = (f16)b.z; h[7] = (f16)b.w;
    return h;
}

template <int ACC, int RELU>
__global__ __launch_bounds__(256) void mgemm_kernel(const float* __restrict__ A,
                                                    const f16* __restrict__ Bp,
                                                    float* __restrict__ C,
                                                    int M, int N, int K, int ldc) {
    __shared__ __align__(16) f16 As[4096];   // 128r x 32k, fragment-linear
    __shared__ __align__(16) f16 Bs[4096];   // 32k x 128n, fragment-linear
    const int tid  = threadIdx.x;
    const int lane = tid & 63, wid = tid >> 6;
    const int wr = wid >> 1, wc = wid & 1;
    const int bm = blockIdx.y * 128, bn = blockIdx.x * 128;
    const int ktiles = K >> 5;
    const f16* btile = Bp + (size_t)blockIdx.x * ktiles * 4096;

    // A staging: thread owns slots tid and tid+256
    const int s0 = tid, s1 = tid + 256;
    const int r0 = ((s0 >> 6) << 4) + (s0 & 15), kk0 = ((s0 >> 4) & 3) << 3;
    const int r1 = ((s1 >> 6) << 4) + (s1 & 15), kk1 = ((s1 >> 4) & 3) << 3;
    const float* a0 = A + (size_t)(bm + r0) * K + kk0;
    const float* a1 = A + (size_t)(bm + r1) * K + kk1;

    f32x4 acc[4][4];
#pragma unroll
    for (int i = 0; i < 4; ++i)
#pragma unroll
        for (int j = 0; j < 4; ++j) acc[i][j] = (f32x4){0.f, 0.f, 0.f, 0.f};

    for (int kt = 0; kt < ktiles; ++kt) {
        const int k0 = kt << 5;
        // B tile: pure 16B-linear copy of packed fp16
        const uint4 bv0 = *(const uint4*)(btile + (size_t)kt * 4096 + tid * 8);
        const uint4 bv1 = *(const uint4*)(btile + (size_t)kt * 4096 + 2048 + tid * 8);
        // A tile: fp32 load + convert
        const float4 f00 = *(const float4*)(a0 + k0);
        const float4 f01 = *(const float4*)(a0 + k0 + 4);
        const float4 f10 = *(const float4*)(a1 + k0);
        const float4 f11 = *(const float4*)(a1 + k0 + 4);
        const half8 h0 = cvt8(f00, f01);
        const half8 h1 = cvt8(f10, f11);

        __syncthreads();   // previous compute done reading LDS
        *(uint4*)((char*)Bs + tid * 16)        = bv0;
        *(uint4*)((char*)Bs + 4096 + tid * 16) = bv1;
        *(half8*)((char*)As + s0 * 16) = h0;
        *(half8*)((char*)As + s1 * 16) = h1;
        __syncthreads();

        half8 af[4], bf[4];
#pragma unroll
        for (int i = 0; i < 4; ++i)
            af[i] = *(half8*)((char*)As + (wr * 4 + i) * 1024 + lane * 16);
#pragma unroll
        for (int j = 0; j < 4; ++j)
            bf[j] = *(half8*)((char*)Bs + (wc * 4 + j) * 1024 + lane * 16);
#pragma unroll
        for (int i = 0; i < 4; ++i)
#pragma unroll
            for (int j = 0; j < 4; ++j)
                acc[i][j] = __builtin_amdgcn_mfma_f32_16x16x32_f16(af[i], bf[j], acc[i][j], 0, 0, 0);
    }

    // epilogue: C/D layout col=lane&15, row=(lane>>4)*4+reg (HW-verified)
#pragma unroll
    for (int i = 0; i < 4; ++i) {
        const int row0 = bm + wr * 64 + i * 16 + ((lane >> 4) << 2);
#pragma unroll
        for (int j = 0; j < 4; ++j) {
            const int col = bn + wc * 64 + j * 16 + (lane & 15);
            float* cp = C + (size_t)row0 * ldc + col;
#pragma unroll
            for (int r = 0; r < 4; ++r) {
                float v = acc[i][j][r];
                if (ACC) v += cp[(size_t)r * ldc];
                if (RELU) v = fmaxf(v, 0.0f);
                cp[(size_t)r * ldc] = v;
            }
        }
    }
}

static inline void launch_mgemm(hipStream_t st, const float* A, const f16* Bp, float* C,
                                int M, int N, int K, int ldc, bool acc, bool relu) {
    dim3 g(N >> 7, M >> 7), blk(256);
    if (acc)       mgemm_kernel<1, 0><<<g, blk, 0, st>>>(A, Bp, C, M, N, K, ldc);
    else if (relu) mgemm_kernel<0, 1><<<g, blk, 0, st>>>(A, Bp, C, M, N, K, ldc);
    else           mgemm_kernel<0, 0><<<g, blk, 0, st>>>(A, Bp, C, M, N, K, ldc);
}

static inline void launch_pack(hipStream_t st, const float* w0, const float* w1, const float* w2,
                               f16* out, int K, int Nw, int nw) {
    dim3 g(Nw >> 7, K >> 5, nw), blk(256);
    pack_kernel<<<g, blk, 0, st>>>(w0, w1, w2, out, Nw);
}

// ---------------- attention scores: sc[b,h,i,j] = q.k + bias, masked ----------------
// q,k live in fused qkv buffer: row stride QKVLD, head offset h*64
__global__ __launch_bounds__(256) void attn_scores_kernel(const float* __restrict__ q,
                                                          const float* __restrict__ k,
                                                          float* __restrict__ sc,
                                                          const float* __restrict__ rel,
                                                          const int* __restrict__ lut,
                                                          const int* __restrict__ qtok,
                                                          const int* __restrict__ ktok,
                                                          int causal) {
    __shared__ float qs[32][65];
    __shared__ float ks[32][65];
    const int j0 = blockIdx.x * 32, i0 = blockIdx.y * 32;
    const int bh = blockIdx.z;
    const int b = bh / Hh, hh = bh % Hh;
    const int tid = threadIdx.x;
    const int tx = tid & 31, ty = tid >> 5;

    if (causal && j0 > i0 + 31) {
        int j = j0 + tx;
#pragma unroll
        for (int ii = 0; ii < 4; ++ii) {
            int i = i0 + ty * 4 + ii;
            sc[(((size_t)(b * Hh + hh)) * Sq + i) * Sq + j] = NEG_INF_F;
        }
        return;
    }

#pragma unroll
    for (int it = 0; it < 8; ++it) {
        int l = it * 256 + tid;
        int r = l >> 6, c = l & 63;
        qs[r][c] = q[(size_t)(b * Sq + i0 + r) * QKVLD + hh * HDm + c];
        ks[r][c] = k[(size_t)(b * Sq + j0 + r) * QKVLD + hh * HDm + c];
    }
    __syncthreads();

    float acc[4] = {0.f, 0.f, 0.f, 0.f};
    for (int hd = 0; hd < HDm; ++hd) {
        float kv = ks[tx][hd];
#pragma unroll
        for (int ii = 0; ii < 4; ++ii) acc[ii] += qs[ty * 4 + ii][hd] * kv;
    }

    int j = j0 + tx;
    int kvalid = ktok[b * Sq + j] > 0;
#pragma unroll
    for (int ii = 0; ii < 4; ++ii) {
        int i = i0 + ty * 4 + ii;
        float v = acc[ii];
        if (rel) v += rel[hh * NBK + lut[j - i + 511]];
        bool ok = kvalid && (qtok[b * Sq + i] > 0);
        if (causal && j > i) ok = false;
        sc[(((size_t)(b * Hh + hh)) * Sq + i) * Sq + j] = ok ? v : NEG_INF_F;
    }
}

// ---------------- softmax over last dim (row length 512), in place ----------------
__global__ __launch_bounds__(256) void softmax_kernel(float* __restrict__ s) {
    __shared__ float red[8];
    float* row = s + (size_t)blockIdx.x * Sq;
    int tid = threadIdx.x;
    float v0 = row[tid], v1 = row[tid + 256];
    float m = fmaxf(v0, v1);
    for (int o = 32; o; o >>= 1) m = fmaxf(m, __shfl_down(m, o, 64));
    int wid = tid >> 6, lane = tid & 63;
    if (lane == 0) red[wid] = m;
    __syncthreads();
    if (tid == 0) red[4] = fmaxf(fmaxf(red[0], red[1]), fmaxf(red[2], red[3]));
    __syncthreads();
    m = red[4];
    float e0 = __expf(v0 - m), e1 = __expf(v1 - m);
    float sum = e0 + e1;
    for (int o = 32; o; o >>= 1) sum += __shfl_down(sum, o, 64);
    if (lane == 0) red[wid] = sum;
    __syncthreads();
    if (tid == 0) red[5] = red[0] + red[1] + red[2] + red[3];
    __syncthreads();
    float inv = 1.0f / red[5];
    row[tid] = e0 * inv;
    row[tid + 256] = e1 * inv;
}

// ---------------- P @ V: ctx[b,i,h,hd] = sum_j p[b,h,i,j] v[b,j,h,hd] ----------------
// v lives in fused qkv buffer (stride QKVLD); ctx output stride Dm
__global__ __launch_bounds__(256) void attn_pv_kernel(const float* __restrict__ p,
                                                      const float* __restrict__ v,
                                                      float* __restrict__ ctx) {
    __shared__ float ps[32][33];
    __shared__ float vs[32][64];
    const int i0 = blockIdx.x * 32;
    const int bh = blockIdx.y;
    const int b = bh / Hh, hh = bh % Hh;
    const int tid = threadIdx.x;
    const int hd = tid & 63, iq = tid >> 6;
    float acc[8];
#pragma unroll
    for (int ii = 0; ii < 8; ++ii) acc[ii] = 0.0f;

    for (int jt = 0; jt < 16; ++jt) {
        int j0 = jt * 32;
#pragma unroll
        for (int it = 0; it < 4; ++it) {
            int l = it * 256 + tid;
            int r = l >> 5, c = l & 31;
            ps[r][c] = p[(((size_t)(b * Hh + hh)) * Sq + i0 + r) * Sq + j0 + c];
        }
#pragma unroll
        for (int it = 0; it < 8; ++it) {
            int l = it * 256 + tid;
            int r = l >> 6, c = l & 63;
            vs[r][c] = v[(size_t)(b * Sq + j0 + r) * QKVLD + hh * HDm + c];
        }
        __syncthreads();
#pragma unroll
        for (int jj = 0; jj < 32; ++jj) {
            float vv = vs[jj][hd];
#pragma unroll
            for (int ii = 0; ii < 8; ++ii) acc[ii] += ps[iq + 4 * ii][jj] * vv;
        }
        __syncthreads();
    }
#pragma unroll
    for (int ii = 0; ii < 8; ++ii) {
        int i = i0 + iq + 4 * ii;
        ctx[((size_t)(b * Sq + i) * Hh + hh) * HDm + hd] = acc[ii];
    }
}

// ---------------- orchestration ----------------
extern "C" void kernel_launch(void* const* d_in, const int* in_sizes, int n_in,
                              void* d_out, int out_size, void* d_ws, size_t ws_size,
                              hipStream_t stream) {
    (void)in_sizes; (void)n_in; (void)out_size; (void)ws_size;
    const float* emb      = (const float*)d_in[0];
    const float* rel_enc  = (const float*)d_in[1];
    const float* rel_dec  = (const float*)d_in[2];
    const float* enc_ln1  = (const float*)d_in[3];
    const float* enc_wq   = (const float*)d_in[4];
    const float* enc_wk   = (const float*)d_in[5];
    const float* enc_wv   = (const float*)d_in[6];
    const float* enc_wo   = (const float*)d_in[7];
    const float* enc_ln2  = (const float*)d_in[8];
    const float* enc_wi   = (const float*)d_in[9];
    const float* enc_wmo  = (const float*)d_in[10];
    const float* enc_nrm  = (const float*)d_in[11];
    const float* dec_ln1  = (const float*)d_in[12];
    const float* dec_sq   = (const float*)d_in[13];
    const float* dec_sk   = (const float*)d_in[14];
    const float* dec_sv   = (const float*)d_in[15];
    const float* dec_so   = (const float*)d_in[16];
    const float* dec_ln2  = (const float*)d_in[17];
    const float* dec_cq   = (const float*)d_in[18];
    const float* dec_ck   = (const float*)d_in[19];
    const float* dec_cv   = (const float*)d_in[20];
    const float* dec_co   = (const float*)d_in[21];
    const float* dec_ln3  = (const float*)d_in[22];
    const float* dec_wi   = (const float*)d_in[23];
    const float* dec_wmo  = (const float*)d_in[24];
    const float* dec_nrm  = (const float*)d_in[25];
    const float* logits_w = (const float*)d_in[26];
    const int* enc_tok    = (const int*)d_in[27];
    const int* dec_in_tok = (const int*)d_in[28];
    const int* dec_tgt    = (const int*)d_in[29];
    float* out = (float*)d_out;

    // workspace layout (floats)
    const size_t BSD = (size_t)NT * Dm;                 // 1,572,864
    float* ws   = (float*)d_ws;
    float* x    = ws;                          // activations [NT, D]
    float* h    = x + BSD;                     // normed input / ctx
    float* qkv  = h + BSD;                     // fused q|k|v [NT, 2304]
    float* enc  = qkv + (size_t)NT * QKVLD;    // encoder output
    float* big  = enc + BSD;                   // scores [B*H*S*S] / MLP hidden / logits pack
    f16*   pk0  = (f16*)(big + (size_t)Bz * Hh * Sq * Sq);
    f16*   pk1  = pk0 + (size_t)Dm * Mf;       // 2 pack slots, each D*M fp16
    int*   lut_e = (int*)(pk1 + (size_t)Dm * Mf);
    int*   lut_d = lut_e + 1024;

    const size_t Wqkv = (size_t)Dm * Hh * HDm;   // 589824 per layer
    const size_t Wmlp = (size_t)Dm * Mf;         // 2359296 per layer

    dim3 blk(256);
    build_lut_kernel<<<dim3(4), blk, 0, stream>>>(lut_e, lut_d);

    // ================= Encoder =================
    embed_kernel<<<dim3(NT), blk, 0, stream>>>(emb, enc_tok, x);
    for (int l = 0; l < Ll; ++l) {
        rmsnorm_kernel<<<dim3(NT), blk, 0, stream>>>(x, enc_ln1 + (size_t)l * Dm, h);
        launch_pack(stream, enc_wq + l * Wqkv, enc_wk + l * Wqkv, enc_wv + l * Wqkv, pk0, Dm, Dm, 3);
        launch_mgemm(stream, h, pk0, qkv, NT, QKVLD, Dm, QKVLD, false, false);
        attn_scores_kernel<<<dim3(16, 16, Bz * Hh), blk, 0, stream>>>(
            qkv, qkv + Dm, big, rel_enc, lut_e, enc_tok, enc_tok, 0);
        softmax_kernel<<<dim3(Bz * Hh * Sq), blk, 0, stream>>>(big);
        attn_pv_kernel<<<dim3(16, Bz * Hh), blk, 0, stream>>>(big, qkv + 2 * Dm, h);
        launch_pack(stream, enc_wo + l * Wqkv, nullptr, nullptr, pk1, Dm, Dm, 1);
        launch_mgemm(stream, h, pk1, x, NT, Dm, Dm, Dm, true, false);          // x += ctx@wo
        rmsnorm_kernel<<<dim3(NT), blk, 0, stream>>>(x, enc_ln2 + (size_t)l * Dm, h);
        launch_pack(stream, enc_wi + l * Wmlp, nullptr, nullptr, pk0, Dm, Mf, 1);
        launch_mgemm(stream, h, pk0, big, NT, Mf, Dm, Mf, false, true);        // relu(h@wi)
        launch_pack(stream, enc_wmo + l * Wmlp, nullptr, nullptr, pk1, Mf, Dm, 1);
        launch_mgemm(stream, big, pk1, x, NT, Dm, Mf, Dm, true, false);        // x += hid@wmo
    }
    rmsnorm_kernel<<<dim3(NT), blk, 0, stream>>>(x, enc_nrm, enc);

    // ================= Decoder =================
    embed_kernel<<<dim3(NT), blk, 0, stream>>>(emb, dec_in_tok, x);
    for (int l = 0; l < Ll; ++l) {
        // self-attention (causal)
        rmsnorm_kernel<<<dim3(NT), blk, 0, stream>>>(x, dec_ln1 + (size_t)l * Dm, h);
        launch_pack(stream, dec_sq + l * Wqkv, dec_sk + l * Wqkv, dec_sv + l * Wqkv, pk0, Dm, Dm, 3);
        launch_mgemm(stream, h, pk0, qkv, NT, QKVLD, Dm, QKVLD, false, false);
        attn_scores_kernel<<<dim3(16, 16, Bz * Hh), blk, 0, stream>>>(
            qkv, qkv + Dm, big, rel_dec, lut_d, dec_tgt, dec_tgt, 1);
        softmax_kernel<<<dim3(Bz * Hh * Sq), blk, 0, stream>>>(big);
        attn_pv_kernel<<<dim3(16, Bz * Hh), blk, 0, stream>>>(big, qkv + 2 * Dm, h);
        launch_pack(stream, dec_so + l * Wqkv, nullptr, nullptr, pk1, Dm, Dm, 1);
        launch_mgemm(stream, h, pk1, x, NT, Dm, Dm, Dm, true, false);
        // cross-attention
        rmsnorm_kernel<<<dim3(NT), blk, 0, stream>>>(x, dec_ln2 + (size_t)l * Dm, h);
        launch_pack(stream, dec_cq + l * Wqkv, nullptr, nullptr, pk0, Dm, Dm, 1);
        launch_mgemm(stream, h, pk0, qkv, NT, Dm, Dm, QKVLD, false, false);    // q part
        launch_pack(stream, dec_ck + l * Wqkv, dec_cv + l * Wqkv, nullptr, pk1, Dm, Dm, 2);
        launch_mgemm(stream, enc, pk1, qkv + Dm, NT, 2 * Dm, Dm, QKVLD, false, false); // k|v
        attn_scores_kernel<<<dim3(16, 16, Bz * Hh), blk, 0, stream>>>(
            qkv, qkv + Dm, big, nullptr, nullptr, dec_tgt, enc_tok, 0);
        softmax_kernel<<<dim3(Bz * Hh * Sq), blk, 0, stream>>>(big);
        attn_pv_kernel<<<dim3(16, Bz * Hh), blk, 0, stream>>>(big, qkv + 2 * Dm, h);
        launch_pack(stream, dec_co + l * Wqkv, nullptr, nullptr, pk0, Dm, Dm, 1);
        launch_mgemm(stream, h, pk0, x, NT, Dm, Dm, Dm, true, false);
        // MLP
        rmsnorm_kernel<<<dim3(NT), blk, 0, stream>>>(x, dec_ln3 + (size_t)l * Dm, h);
        launch_pack(stream, dec_wi + l * Wmlp, nullptr, nullptr, pk1, Dm, Mf, 1);
        launch_mgemm(stream, h, pk1, big, NT, Mf, Dm, Mf, false, true);
        launch_pack(stream, dec_wmo + l * Wmlp, nullptr, nullptr, pk0, Mf, Dm, 1);
        launch_mgemm(stream, big, pk0, x, NT, Dm, Mf, Dm, true, false);
    }
    rmsnorm_kernel<<<dim3(NT), blk, 0, stream>>>(x, dec_nrm, h);

    // ================= logits =================
    // scores/hidden dead: overlay logits_w pack into `big` (needs 12.34M floats <= 12.58M)
    f16* pkL = (f16*)big;
    launch_pack(stream, logits_w, nullptr, nullptr, pkL, Dm, Vv, 1);
    launch_mgemm(stream, h, pkL, out, NT, Vv, Dm, Vv, false, false);
}

// Round 2
// 5097.758 us; speedup vs baseline: 1.8312x; 1.8312x over previous
//
#include <hip/hip_runtime.h>
#include <cstddef>
#include <cstdint>

// ---------------- T5-Base config (fixed) ----------------
constexpr int Bz  = 4;
constexpr int Sq  = 512;     // SE == SD == 512
constexpr int Dm  = 768;
constexpr int Hh  = 12;
constexpr int HDm = 64;
constexpr int Mf  = 3072;
constexpr int Ll  = 6;
constexpr int Vv  = 32128;
constexpr int NT  = Bz * Sq;          // 2048 token rows
constexpr int NBK = 32;               // num relpos buckets
constexpr int QKVLD = 3 * Dm;         // 2304: fused qkv row stride
#define NEG_INF_F (-1e10f)

typedef _Float16 f16;
typedef _Float16 half8 __attribute__((ext_vector_type(8)));
typedef _Float16 half4 __attribute__((ext_vector_type(4)));
typedef float f32x4 __attribute__((ext_vector_type(4)));

// ---------------- relative-position bucket LUT ----------------
__global__ void build_lut_kernel(int* __restrict__ lut_enc, int* __restrict__ lut_dec) {
    int t = blockIdx.x * blockDim.x + threadIdx.x;
    if (t >= 1023) return;
    int delta = t - 511;          // j - i
    {   // encoder: bidirectional, 16 buckets after halving, max_exact 8
        int n = -delta;
        int ret = 0;
        if (n < 0) { ret = 16; n = -n; }
        int b;
        if (n < 8) b = ret + n;
        else {
            int v = 8 + (int)(logf((float)n / 8.0f) / logf(16.0f) * 8.0f);
            if (v > 15) v = 15;
            b = ret + v;
        }
        lut_enc[t] = b;
    }
    {   // decoder self: unidirectional, 32 buckets, max_exact 16
        int n = delta < 0 ? -delta : 0;
        int b;
        if (n < 16) b = n;
        else {
            b = 16 + (int)(logf((float)n / 16.0f) / logf(8.0f) * 16.0f);
            if (b > 31) b = 31;
        }
        lut_dec[t] = b;
    }
}

// ---------------- embedding gather ----------------
__global__ void embed_kernel(const float* __restrict__ emb, const int* __restrict__ tok,
                             float* __restrict__ out) {
    int r = blockIdx.x;
    int t = tok[r];
    const float* e = emb + (size_t)t * Dm;
    float* o = out + (size_t)r * Dm;
    for (int d = threadIdx.x; d < Dm; d += 256) o[d] = e[d];
}

// ---------------- RMS norm (row = 768) ----------------
__global__ __launch_bounds__(256) void rmsnorm_kernel(const float* __restrict__ in,
                                                      const float* __restrict__ scale,
                                                      float* __restrict__ out) {
    __shared__ float red[8];
    const float* row = in + (size_t)blockIdx.x * Dm;
    float* orow      = out + (size_t)blockIdx.x * Dm;
    int tid = threadIdx.x;
    float a = row[tid], b = row[tid + 256], c = row[tid + 512];
    float s = a * a + b * b + c * c;
    for (int o = 32; o; o >>= 1) s += __shfl_down(s, o, 64);
    int wid = tid >> 6, lane = tid & 63;
    if (lane == 0) red[wid] = s;
    __syncthreads();
    if (tid == 0) red[4] = red[0] + red[1] + red[2] + red[3];
    __syncthreads();
    float r = 1.0f / sqrtf(red[4] * (1.0f / (float)Dm) + 1e-6f);
    orow[tid]       = a * r * scale[tid];
    orow[tid + 256] = b * r * scale[tid + 256];
    orow[tid + 512] = c * r * scale[tid + 512];
}

// ---------------- weight pack: fp32 [K][N] -> fragment-linear fp16 tiles ----------
__global__ __launch_bounds__(256) void pack_kernel(const float* __restrict__ w0,
                                                   const float* __restrict__ w1,
                                                   const float* __restrict__ w2,
                                                   f16* __restrict__ out,
                                                   int Nw) {
    const float* w = (blockIdx.z == 0) ? w0 : (blockIdx.z == 1 ? w1 : w2);
    const int ktiles = gridDim.y;
    const int nt = blockIdx.z * gridDim.x + blockIdx.x;
    const int kt = blockIdx.y;
    f16* otile = out + ((size_t)nt * ktiles + kt) * 4096;
    const int n0 = blockIdx.x * 128, k0 = kt * 32;
    const int tid = threadIdx.x;
#pragma unroll
    for (int p = 0; p < 2; ++p) {
        int s  = tid + p * 256;
        int nn = ((s >> 6) << 4) + (s & 15);
        int kk = ((s >> 4) & 3) << 3;
        const float* src = w + (size_t)(k0 + kk) * Nw + n0 + nn;
        half8 h;
#pragma unroll
        for (int j = 0; j < 8; ++j) h[j] = (f16)src[(size_t)j * Nw];
        *(half8*)((char*)otile + s * 16) = h;
    }
}

// ---------------- MFMA fp16 GEMM (unchanged from round 1) ------------
__device__ inline half8 cvt8(float4 a, float4 b) {
    half8 h;
    h[0] = (f16)a.x; h[1] = (f16)a.y; h[2] = (f16)a.z; h[3] = (f16)a.w;
    h[4] = (f16)b.x; h[5] = (f16)b.y; h[6] = (f16)b.z; h[7] = (f16)b.w;
    return h;
}

template <int ACC, int RELU>
__global__ __launch_bounds__(256) void mgemm_kernel(const float* __restrict__ A,
                                                    const f16* __restrict__ Bp,
                                                    float* __restrict__ C,
                                                    int M, int N, int K, int ldc) {
    __shared__ __align__(16) f16 As[4096];   // 128r x 32k, fragment-linear
    __shared__ __align__(16) f16 Bs[4096];   // 32k x 128n, fragment-linear
    const int tid  = threadIdx.x;
    const int lane = tid & 63, wid = tid >> 6;
    const int wr = wid >> 1, wc = wid & 1;
    const int bm = blockIdx.y * 128, bn = blockIdx.x * 128;
    const int ktiles = K >> 5;
    const f16* btile = Bp + (size_t)blockIdx.x * ktiles * 4096;

    const int s0 = tid, s1 = tid + 256;
    const int r0 = ((s0 >> 6) << 4) + (s0 & 15), kk0 = ((s0 >> 4) & 3) << 3;
    const int r1 = ((s1 >> 6) << 4) + (s1 & 15), kk1 = ((s1 >> 4) & 3) << 3;
    const float* a0 = A + (size_t)(bm + r0) * K + kk0;
    const float* a1 = A + (size_t)(bm + r1) * K + kk1;

    f32x4 acc[4][4];
#pragma unroll
    for (int i = 0; i < 4; ++i)
#pragma unroll
        for (int j = 0; j < 4; ++j) acc[i][j] = (f32x4){0.f, 0.f, 0.f, 0.f};

    for (int kt = 0; kt < ktiles; ++kt) {
        const int k0 = kt << 5;
        const uint4 bv0 = *(const uint4*)(btile + (size_t)kt * 4096 + tid * 8);
        const uint4 bv1 = *(const uint4*)(btile + (size_t)kt * 4096 + 2048 + tid * 8);
        const float4 f00 = *(const float4*)(a0 + k0);
        const float4 f01 = *(const float4*)(a0 + k0 + 4);
        const float4 f10 = *(const float4*)(a1 + k0);
        const float4 f11 = *(const float4*)(a1 + k0 + 4);
        const half8 h0 = cvt8(f00, f01);
        const half8 h1 = cvt8(f10, f11);

        __syncthreads();
        *(uint4*)((char*)Bs + tid * 16)        = bv0;
        *(uint4*)((char*)Bs + 4096 + tid * 16) = bv1;
        *(half8*)((char*)As + s0 * 16) = h0;
        *(half8*)((char*)As + s1 * 16) = h1;
        __syncthreads();

        half8 af[4], bf[4];
#pragma unroll
        for (int i = 0; i < 4; ++i)
            af[i] = *(half8*)((char*)As + (wr * 4 + i) * 1024 + lane * 16);
#pragma unroll
        for (int j = 0; j < 4; ++j)
            bf[j] = *(half8*)((char*)Bs + (wc * 4 + j) * 1024 + lane * 16);
#pragma unroll
        for (int i = 0; i < 4; ++i)
#pragma unroll
            for (int j = 0; j < 4; ++j)
                acc[i][j] = __builtin_amdgcn_mfma_f32_16x16x32_f16(af[i], bf[j], acc[i][j], 0, 0, 0);
    }

#pragma unroll
    for (int i = 0; i < 4; ++i) {
        const int row0 = bm + wr * 64 + i * 16 + ((lane >> 4) << 2);
#pragma unroll
        for (int j = 0; j < 4; ++j) {
            const int col = bn + wc * 64 + j * 16 + (lane & 15);
            float* cp = C + (size_t)row0 * ldc + col;
#pragma unroll
            for (int r = 0; r < 4; ++r) {
                float v = acc[i][j][r];
                if (ACC) v += cp[(size_t)r * ldc];
                if (RELU) v = fmaxf(v, 0.0f);
                cp[(size_t)r * ldc] = v;
            }
        }
    }
}

static inline void launch_mgemm(hipStream_t st, const float* A, const f16* Bp, float* C,
                                int M, int N, int K, int ldc, bool acc, bool relu) {
    dim3 g(N >> 7, M >> 7), blk(256);
    if (acc)       mgemm_kernel<1, 0><<<g, blk, 0, st>>>(A, Bp, C, M, N, K, ldc);
    else if (relu) mgemm_kernel<0, 1><<<g, blk, 0, st>>>(A, Bp, C, M, N, K, ldc);
    else           mgemm_kernel<0, 0><<<g, blk, 0, st>>>(A, Bp, C, M, N, K, ldc);
}

static inline void launch_pack(hipStream_t st, const float* w0, const float* w1, const float* w2,
                               f16* out, int K, int Nw, int nw) {
    dim3 g(Nw >> 7, K >> 5, nw), blk(256);
    pack_kernel<<<g, blk, 0, st>>>(w0, w1, w2, out, Nw);
}

// ---------------- fused flash attention (MFMA fp16, fp32 online softmax) --------
// Computes S^T = K @ Q^T per (b,h), so both operands stage fragment-linear and the
// softmax column (q-row) is lane-local. P^T -> PV A-frags via 16 shuffles (no LDS).
// Q-tile 64, KV-tile 64, 4 waves x 16 q-rows each, grid (8, 48).
__device__ inline uint32_t pack2(float a, float b) {
    union { f16 h[2]; uint32_t u; } u_;
    u_.h[0] = (f16)a; u_.h[1] = (f16)b;
    return u_.u;
}

template <int CAUSAL, int HASREL>
__global__ __launch_bounds__(256) void fattn_kernel(const float* __restrict__ q,
                                                    const float* __restrict__ k,
                                                    const float* __restrict__ v,
                                                    float* __restrict__ ctx,
                                                    const float* __restrict__ rel,
                                                    const int* __restrict__ lut,
                                                    const int* __restrict__ qtok,
                                                    const int* __restrict__ ktok) {
    __shared__ __align__(16) f16 Qs[4096];       // 64 rows x 64 d, fragment-linear
    __shared__ __align__(16) f16 Ks[4096];       // 64 kv  x 64 d, fragment-linear
    __shared__ __align__(16) f16 Vt[64 * 72];    // Vt[d][j], stride 72 (bank-uniform)
    __shared__ float biasAll[576];               // bias by (j - i) delta for this block
    __shared__ __align__(4) unsigned char kvb[512];

    const int tid  = threadIdx.x;
    const int lane = tid & 63, wid = tid >> 6;
    const int il = lane & 15, G = lane >> 4;
    const int i0 = blockIdx.x * 64;
    const int bh = blockIdx.y;
    const int b = bh / Hh, hh = bh % Hh;

    // ---- prologue staging ----
    kvb[tid]       = (unsigned char)(ktok[b * Sq + tid] > 0);
    kvb[tid + 256] = (unsigned char)(ktok[b * Sq + tid + 256] > 0);
    if (HASREL) {
        for (int t = tid; t < 575; t += 256)
            biasAll[t] = rel[hh * NBK + lut[t - i0 + 448]];
    }
#pragma unroll
    for (int p = 0; p < 2; ++p) {           // Q fragment-linear stage
        int ss = tid + p * 256;
        int reg = ss >> 6, ln = ss & 63;
        int row = (reg >> 1) * 16 + (ln & 15);
        int d   = (reg & 1) * 32 + ((ln >> 4) << 3);
        const float* src = q + (size_t)(b * Sq + i0 + row) * QKVLD + hh * HDm + d;
        float4 f0 = *(const float4*)src;
        float4 f1 = *(const float4*)(src + 4);
        *(half8*)(Qs + ss * 8) = cvt8(f0, f1);
    }
    __syncthreads();

    const int qrow = i0 + wid * 16 + il;
    const int qv = qtok[b * Sq + qrow] > 0;

    half8 bq[2];
#pragma unroll
    for (int kc = 0; kc < 2; ++kc)
        bq[kc] = *(const half8*)(Qs + (wid * 2 + kc) * 512 + lane * 8);

    f32x4 o[4];
#pragma unroll
    for (int nf = 0; nf < 4; ++nf) o[nf] = (f32x4){0.f, 0.f, 0.f, 0.f};
    float mrun = -1e30f, lrun = 0.0f;

    for (int kt = 0; kt < 8; ++kt) {
        const int j0 = kt * 64;
        const bool fullmask = CAUSAL && (j0 > i0 + 63);
        __syncthreads();
        if (!fullmask) {
#pragma unroll
            for (int p = 0; p < 2; ++p) {   // K fragment-linear stage
                int ss = tid + p * 256;
                int reg = ss >> 6, ln = ss & 63;
                int row = (reg >> 1) * 16 + (ln & 15);
                int d   = (reg & 1) * 32 + ((ln >> 4) << 3);
                const float* src = k + (size_t)(b * Sq + j0 + row) * QKVLD + hh * HDm + d;
                float4 f0 = *(const float4*)src;
                float4 f1 = *(const float4*)(src + 4);
                *(half8*)(Ks + ss * 8) = cvt8(f0, f1);
            }
        }
#pragma unroll
        for (int it = 0; it < 4; ++it) {    // V transpose stage: Vt[d][j]
            int d  = tid & 63;
            int jq = (tid >> 6) + it * 4;
            const float* vp = v + (size_t)(b * Sq + j0 + jq * 4) * QKVLD + hh * HDm + d;
            half4 hv;
#pragma unroll
            for (int jj = 0; jj < 4; ++jj) hv[jj] = (f16)vp[(size_t)jj * QKVLD];
            *(half4*)(Vt + d * 72 + jq * 4) = hv;
        }
        __syncthreads();

        // ---- S^T = K @ Q^T (rows j, cols i; lane owns col i = wid*16+il) ----
        f32x4 s[4];
        if (!fullmask) {
#pragma unroll
            for (int mf = 0; mf < 4; ++mf) {
                f32x4 acc = (f32x4){0.f, 0.f, 0.f, 0.f};
#pragma unroll
                for (int kc = 0; kc < 2; ++kc) {
                    half8 ak = *(const half8*)(Ks + (mf * 2 + kc) * 512 + lane * 8);
                    acc = __builtin_amdgcn_mfma_f32_16x16x32_f16(ak, bq[kc], acc, 0, 0, 0);
                }
                s[mf] = acc;
            }
            uint32_t kb[4];
#pragma unroll
            for (int mf = 0; mf < 4; ++mf)
                kb[mf] = *(const uint32_t*)(kvb + j0 + mf * 16 + G * 4);
            const bool fastm = __all(qv) &&
                __all((kb[0] & kb[1] & kb[2] & kb[3]) == 0x01010101u);
            const bool needC = CAUSAL && (j0 + 63 > i0 + wid * 16);
#pragma unroll
            for (int mf = 0; mf < 4; ++mf) {
#pragma unroll
                for (int r = 0; r < 4; ++r) {
                    int jl = mf * 16 + G * 4 + r;
                    float val = s[mf][r];
                    if (HASREL) val += biasAll[jl + j0 + 63 - wid * 16 - il];
                    bool ok = fastm ? true
                                    : (qv && (((kb[mf] >> (8 * r)) & 255u) != 0u));
                    if (needC) ok = ok && (j0 + jl <= i0 + wid * 16 + il);
                    s[mf][r] = ok ? val : NEG_INF_F;
                }
            }
        } else {
#pragma unroll
            for (int mf = 0; mf < 4; ++mf)
                s[mf] = (f32x4){NEG_INF_F, NEG_INF_F, NEG_INF_F, NEG_INF_F};
        }

        // ---- online softmax (per column i; m,l,scale lane-local) ----
        float tm = s[0][0];
#pragma unroll
        for (int mf = 0; mf < 4; ++mf)
#pragma unroll
            for (int r = 0; r < 4; ++r) tm = fmaxf(tm, s[mf][r]);
        tm = fmaxf(tm, __shfl_xor(tm, 16, 64));
        tm = fmaxf(tm, __shfl_xor(tm, 32, 64));
        float mnew  = fmaxf(mrun, tm);
        float scale = __expf(mrun - mnew);
        float lsum = 0.f;
#pragma unroll
        for (int mf = 0; mf < 4; ++mf)
#pragma unroll
            for (int r = 0; r < 4; ++r) {
                float pv_ = __expf(s[mf][r] - mnew);
                s[mf][r] = pv_;
                lsum += pv_;
            }
        lsum += __shfl_xor(lsum, 16, 64);
        lsum += __shfl_xor(lsum, 32, 64);
        lrun = lrun * scale + lsum;
        mrun = mnew;
        float sc[4];
#pragma unroll
        for (int r = 0; r < 4; ++r) sc[r] = __shfl(scale, G * 4 + r, 64);
#pragma unroll
        for (int nf = 0; nf < 4; ++nf)
#pragma unroll
            for (int r = 0; r < 4; ++r) o[nf][r] *= sc[r];

        // ---- P^T -> fp16 PV A-frags via group-swap shuffles (i stays lane-local) --
        uint32_t ph[4][2];
#pragma unroll
        for (int mf = 0; mf < 4; ++mf) {
            ph[mf][0] = pack2(s[mf][0], s[mf][1]);
            ph[mf][1] = pack2(s[mf][2], s[mf][3]);
        }
        uint32_t paw[2][4];
        const int base = ((lane >> 4) & 1) * 32 + il;
        const bool hiG = lane >= 32;
#pragma unroll
        for (int w = 0; w < 4; ++w) {
            int sl = base + ((w >> 1) << 4);
            uint32_t v00 = __shfl(ph[0][w & 1], sl, 64);
            uint32_t v01 = __shfl(ph[1][w & 1], sl, 64);
            uint32_t v10 = __shfl(ph[2][w & 1], sl, 64);
            uint32_t v11 = __shfl(ph[3][w & 1], sl, 64);
            paw[0][w] = hiG ? v01 : v00;
            paw[1][w] = hiG ? v11 : v10;
        }

        // ---- O += P @ V ----
#pragma unroll
        for (int kc2 = 0; kc2 < 2; ++kc2) {
            union { uint32_t w[4]; half8 h; } pa;
#pragma unroll
            for (int w = 0; w < 4; ++w) pa.w[w] = paw[kc2][w];
#pragma unroll
            for (int nf = 0; nf < 4; ++nf) {
                half8 bv = *(const half8*)(Vt + (il + 16 * nf) * 72 + kc2 * 32 + G * 8);
                o[nf] = __builtin_amdgcn_mfma_f32_16x16x32_f16(pa.h, bv, o[nf], 0, 0, 0);
            }
        }
    }

    // ---- normalize + write (O C-layout: row i = wid*16 + 4G + r, col d = il + 16nf)
    float inv = 1.0f / lrun;
    float linv[4];
#pragma unroll
    for (int r = 0; r < 4; ++r) linv[r] = __shfl(inv, G * 4 + r, 64);
#pragma unroll
    for (int nf = 0; nf < 4; ++nf) {
#pragma unroll
        for (int r = 0; r < 4; ++r) {
            int row = i0 + wid * 16 + G * 4 + r;
            ctx[(size_t)(b * Sq + row) * Dm + hh * HDm + il + 16 * nf] = o[nf][r] * linv[r];
        }
    }
}

// ---------------- orchestration ----------------
extern "C" void kernel_launch(void* const* d_in, const int* in_sizes, int n_in,
                              void* d_out, int out_size, void* d_ws, size_t ws_size,
                              hipStream_t stream) {
    (void)in_sizes; (void)n_in; (void)out_size; (void)ws_size;
    const float* emb      = (const float*)d_in[0];
    const float* rel_enc  = (const float*)d_in[1];
    const float* rel_dec  = (const float*)d_in[2];
    const float* enc_ln1  = (const float*)d_in[3];
    const float* enc_wq   = (const float*)d_in[4];
    const float* enc_wk   = (const float*)d_in[5];
    const float* enc_wv   = (const float*)d_in[6];
    const float* enc_wo   = (const float*)d_in[7];
    const float* enc_ln2  = (const float*)d_in[8];
    const float* enc_wi   = (const float*)d_in[9];
    const float* enc_wmo  = (const float*)d_in[10];
    const float* enc_nrm  = (const float*)d_in[11];
    const float* dec_ln1  = (const float*)d_in[12];
    const float* dec_sq   = (const float*)d_in[13];
    const float* dec_sk   = (const float*)d_in[14];
    const float* dec_sv   = (const float*)d_in[15];
    const float* dec_so   = (const float*)d_in[16];
    const float* dec_ln2  = (const float*)d_in[17];
    const float* dec_cq   = (const float*)d_in[18];
    const float* dec_ck   = (const float*)d_in[19];
    const float* dec_cv   = (const float*)d_in[20];
    const float* dec_co   = (const float*)d_in[21];
    const float* dec_ln3  = (const float*)d_in[22];
    const float* dec_wi   = (const float*)d_in[23];
    const float* dec_wmo  = (const float*)d_in[24];
    const float* dec_nrm  = (const float*)d_in[25];
    const float* logits_w = (const float*)d_in[26];
    const int* enc_tok    = (const int*)d_in[27];
    const int* dec_in_tok = (const int*)d_in[28];
    const int* dec_tgt    = (const int*)d_in[29];
    float* out = (float*)d_out;

    // workspace layout (floats)
    const size_t BSD = (size_t)NT * Dm;                 // 1,572,864
    float* ws   = (float*)d_ws;
    float* x    = ws;                          // activations [NT, D]
    float* h    = x + BSD;                     // normed input / ctx
    float* qkv  = h + BSD;                     // fused q|k|v [NT, 2304]
    float* enc  = qkv + (size_t)NT * QKVLD;    // encoder output
    float* big  = enc + BSD;                   // MLP hidden / logits pack overlay
    f16*   pk0  = (f16*)(big + (size_t)Bz * Hh * Sq * Sq);
    f16*   pk1  = pk0 + (size_t)Dm * Mf;       // 2 pack slots, each D*M fp16
    int*   lut_e = (int*)(pk1 + (size_t)Dm * Mf);
    int*   lut_d = lut_e + 1024;

    const size_t Wqkv = (size_t)Dm * Hh * HDm;   // 589824 per layer
    const size_t Wmlp = (size_t)Dm * Mf;         // 2359296 per layer

    dim3 blk(256);
    dim3 agrid(Sq / 64, Bz * Hh);
    build_lut_kernel<<<dim3(4), blk, 0, stream>>>(lut_e, lut_d);

    // ================= Encoder =================
    embed_kernel<<<dim3(NT), blk, 0, stream>>>(emb, enc_tok, x);
    for (int l = 0; l < Ll; ++l) {
        rmsnorm_kernel<<<dim3(NT), blk, 0, stream>>>(x, enc_ln1 + (size_t)l * Dm, h);
        launch_pack(stream, enc_wq + l * Wqkv, enc_wk + l * Wqkv, enc_wv + l * Wqkv, pk0, Dm, Dm, 3);
        launch_mgemm(stream, h, pk0, qkv, NT, QKVLD, Dm, QKVLD, false, false);
        fattn_kernel<0, 1><<<agrid, blk, 0, stream>>>(
            qkv, qkv + Dm, qkv + 2 * Dm, h, rel_enc, lut_e, enc_tok, enc_tok);
        launch_pack(stream, enc_wo + l * Wqkv, nullptr, nullptr, pk1, Dm, Dm, 1);
        launch_mgemm(stream, h, pk1, x, NT, Dm, Dm, Dm, true, false);          // x += ctx@wo
        rmsnorm_kernel<<<dim3(NT), blk, 0, stream>>>(x, enc_ln2 + (size_t)l * Dm, h);
        launch_pack(stream, enc_wi + l * Wmlp, nullptr, nullptr, pk0, Dm, Mf, 1);
        launch_mgemm(stream, h, pk0, big, NT, Mf, Dm, Mf, false, true);        // relu(h@wi)
        launch_pack(stream, enc_wmo + l * Wmlp, nullptr, nullptr, pk1, Mf, Dm, 1);
        launch_mgemm(stream, big, pk1, x, NT, Dm, Mf, Dm, true, false);        // x += hid@wmo
    }
    rmsnorm_kernel<<<dim3(NT), blk, 0, stream>>>(x, enc_nrm, enc);

    // ================= Decoder =================
    embed_kernel<<<dim3(NT), blk, 0, stream>>>(emb, dec_in_tok, x);
    for (int l = 0; l < Ll; ++l) {
        // self-attention (causal)
        rmsnorm_kernel<<<dim3(NT), blk, 0, stream>>>(x, dec_ln1 + (size_t)l * Dm, h);
        launch_pack(stream, dec_sq + l * Wqkv, dec_sk + l * Wqkv, dec_sv + l * Wqkv, pk0, Dm, Dm, 3);
        launch_mgemm(stream, h, pk0, qkv, NT, QKVLD, Dm, QKVLD, false, false);
        fattn_kernel<1, 1><<<agrid, blk, 0, stream>>>(
            qkv, qkv + Dm, qkv + 2 * Dm, h, rel_dec, lut_d, dec_tgt, dec_tgt);
        launch_pack(stream, dec_so + l * Wqkv, nullptr, nullptr, pk1, Dm, Dm, 1);
        launch_mgemm(stream, h, pk1, x, NT, Dm, Dm, Dm, true, false);
        // cross-attention
        rmsnorm_kernel<<<dim3(NT), blk, 0, stream>>>(x, dec_ln2 + (size_t)l * Dm, h);
        launch_pack(stream, dec_cq + l * Wqkv, nullptr, nullptr, pk0, Dm, Dm, 1);
        launch_mgemm(stream, h, pk0, qkv, NT, Dm, Dm, QKVLD, false, false);    // q part
        launch_pack(stream, dec_ck + l * Wqkv, dec_cv + l * Wqkv, nullptr, pk1, Dm, Dm, 2);
        launch_mgemm(stream, enc, pk1, qkv + Dm, NT, 2 * Dm, Dm, QKVLD, false, false); // k|v
        fattn_kernel<0, 0><<<agrid, blk, 0, stream>>>(
            qkv, qkv + Dm, qkv + 2 * Dm, h, nullptr, nullptr, dec_tgt, enc_tok);
        launch_pack(stream, dec_co + l * Wqkv, nullptr, nullptr, pk0, Dm, Dm, 1);
        launch_mgemm(stream, h, pk0, x, NT, Dm, Dm, Dm, true, false);
        // MLP
        rmsnorm_kernel<<<dim3(NT), blk, 0, stream>>>(x, dec_ln3 + (size_t)l * Dm, h);
        launch_pack(stream, dec_wi + l * Wmlp, nullptr, nullptr, pk1, Dm, Mf, 1);
        launch_mgemm(stream, h, pk1, big, NT, Mf, Dm, Mf, false, true);
        launch_pack(stream, dec_wmo + l * Wmlp, nullptr, nullptr, pk0, Mf, Dm, 1);
        launch_mgemm(stream, big, pk0, x, NT, Dm, Mf, Dm, true, false);
    }
    rmsnorm_kernel<<<dim3(NT), blk, 0, stream>>>(x, dec_nrm, h);

    // ================= logits =================
    f16* pkL = (f16*)big;
    launch_pack(stream, logits_w, nullptr, nullptr, pkL, Dm, Vv, 1);
    launch_mgemm(stream, h, pkL, out, NT, Vv, Dm, Vv, false, false);
}